// Round 12
// baseline (3024.221 us; speedup 1.0000x reference)
//
#include <hip/hip_runtime.h>
#include <cstdint>

typedef short short8  __attribute__((ext_vector_type(8)));
typedef unsigned short ushort4v __attribute__((ext_vector_type(4)));
typedef unsigned int uint2v __attribute__((ext_vector_type(2)));
typedef float floatx4 __attribute__((ext_vector_type(4)));

#define HID    128
#define NB     32
#define TPB    512
#define NBLK   2048          // 65536 / 32
#define TSTEPS 30
#define MU_OFF 5898240       // 65536*30*3
#define HSZ    4096          // NB*128: one h parity buffer (bf16 units)

// ws layout (bf16 units): A-fragment arrays, PER-WAVE-CONTIGUOUS order:
// element (mt=g*8+w, kt, lane l, jj) stored at (((w*KT+kt)*4+g)*512) + l*8 + jj
// -> per kt one base add, 4 gate loads at +0/+1024/+2048/+3072 bytes (imm-foldable)
#define L0_SZ  81920         // 512*160  (K-ext: [Whh(128)|Wih0(3)|0(29)])
#define L1_SZ  131072        // 512*256  (K-ext: [Wih1(128)|Whh1(128)])
#define ENC0_HI 0
#define ENC0_LO 81920
#define ENC1_HI 163840
#define ENC1_LO 294912
#define DEC0_HI 425984
#define DEC0_LO 507904
#define DEC1_HI 589824
#define DEC1_LO 720896

// v_rcp_f32 (~1 ulp) instead of the IEEE div chain
__device__ __forceinline__ float sigm(float v){
  return __builtin_amdgcn_rcpf(1.f + __expf(-v));
}
__device__ __forceinline__ float tanh_fast(float v){
  return 2.f*__builtin_amdgcn_rcpf(1.f + __expf(-2.f*v)) - 1.f;
}

__device__ __forceinline__ unsigned short f2bf(float f){
  unsigned u = __float_as_uint(f);
  u = (u + 0x7FFF + ((u>>16)&1)) >> 16;     // RNE; inputs finite
  return (unsigned short)u;
}
__device__ __forceinline__ float bf2f(unsigned short b){
  return __uint_as_float(((unsigned)b)<<16);
}
// packed RNE f32->bf16 pair (bit-identical to f2bf for finite inputs)
__device__ __forceinline__ unsigned cvt_pk_bf16(float lo, float hi){
  unsigned r;
  asm("v_cvt_pk_bf16_f32 %0, %1, %2" : "=v"(r) : "v"(lo), "v"(hi));
  return r;
}

// ---------------- prep: swizzle weights into A-fragment order, bf16 hi/lo ----
extern "C" __global__ void __launch_bounds__(256)
prep_frag(const float* __restrict__ eWih0, const float* __restrict__ eWhh0,
          const float* __restrict__ eWih1, const float* __restrict__ eWhh1,
          const float* __restrict__ dWih0, const float* __restrict__ dWhh0,
          const float* __restrict__ dWih1, const float* __restrict__ dWhh1,
          unsigned short* __restrict__ ws)
{
  const int idx = blockIdx.x*256 + threadIdx.x;   // one thread -> one (hi,lo) pair
  int i2, hi_base, lo_base, KT;
  const float* Wa; const float* Wb;
  if (idx < L0_SZ)                { i2=idx;                 hi_base=ENC0_HI; lo_base=ENC0_LO; Wa=eWhh0; Wb=eWih0; KT=5; }
  else if (idx < L0_SZ+L1_SZ)     { i2=idx-L0_SZ;           hi_base=ENC1_HI; lo_base=ENC1_LO; Wa=eWih1; Wb=eWhh1; KT=8; }
  else if (idx < 2*L0_SZ+L1_SZ)   { i2=idx-(L0_SZ+L1_SZ);   hi_base=DEC0_HI; lo_base=DEC0_LO; Wa=dWhh0; Wb=dWih0; KT=5; }
  else                            { i2=idx-(2*L0_SZ+L1_SZ); hi_base=DEC1_HI; lo_base=DEC1_LO; Wa=dWih1; Wb=dWhh1; KT=8; }
  const int jj = i2 & 7, l = (i2>>3)&63, tk = i2>>9;
  const int kt = (KT==5) ? (tk%5) : (tk&7);
  const int mt = (KT==5) ? (tk/5) : (tk>>3);
  const int row = mt*16 + (l&15);
  const int k   = kt*32 + ((l>>4)&3)*8 + jj;
  float w;
  if (KT==5) w = (k<128) ? Wa[row*128+k] : ((k<131) ? Wb[row*3 + (k-128)] : 0.f);
  else       w = (k<128) ? Wa[row*128+k] : Wb[row*128 + (k-128)];
  const unsigned short hi = f2bf(w);
  // per-wave-contiguous output index
  const int w8 = mt & 7, g = mt >> 3;
  const int oidx = (((w8*KT + kt)*4 + g)*512) + l*8 + jj;
  ws[hi_base + oidx] = hi;
  ws[lo_base + oidx] = f2bf(w - bf2f(hi));
}

// ------- fused LSTM: NB=32/block, 8 waves, 2 blocks/CU, h in plain bf16 -----
// 2 co-resident blocks drift out of phase -> cross-block MFMA||VALU overlap
// (m114), confirmed (busy-sum 93-115% in R10/R11).
// R12 vs R11 (all arithmetic-identical): bias hoisted to 32 persistent VGPRs;
// v_cvt_pk_bf16_f32 h-pack; per-wave-contiguous A layout (imm-folded loads);
// s_setprio(1) around MFMA pairs.
extern "C" __global__ void __launch_bounds__(TPB, 4)
lstm_mfma(const float* __restrict__ x,
          const unsigned short* __restrict__ wf,
          const float* __restrict__ enc_b0, const float* __restrict__ enc_b1,
          const float* __restrict__ dec_b0, const float* __restrict__ dec_b1,
          const float* __restrict__ fc_W,  const float* __restrict__ fc_b,
          float* __restrict__ out)
{
  // h element (n,k) at n*128 + (((k>>3) ^ (n&15))<<3) + (k&7), per parity buf
  __shared__ unsigned short h0h[2*HSZ];
  __shared__ unsigned short h1h[2*HSZ];
  __shared__ unsigned short xbh[2*NB*8], xbl[2*NB*8]; // x / mu feedback, 2 parities
  __shared__ unsigned short fcAh[4*512], fcAl[4*512]; // FC weights, A-frag layout
  __shared__ float bias[1024];                         // staging: [b0 | b1]

  const int tid  = threadIdx.x;
  const int w    = tid>>6, l = tid&63;
  const int quad = (l>>4)&3, n15 = l&15;
  const int b0   = blockIdx.x*NB;

  bias[tid]       = enc_b0[tid];
  bias[512 + tid] = enc_b1[tid];
  for (int i=tid;i<2*HSZ;i+=TPB){ h0h[i]=0; h1h[i]=0; }
  xbh[tid]=0; xbl[tid]=0;                   // 2*NB*8 == 512 == TPB
  if (w < 4){                               // FC weights -> LDS A-frags, kt=w
    short8 vh, vl;
#pragma unroll
    for (int jj=0;jj<8;jj++){
      const float f = (n15<6) ? fc_W[n15*HID + w*32 + quad*8 + jj] : 0.f;
      const unsigned short hi = f2bf(f);
      vh[jj] = (short)hi;
      vl[jj] = (short)f2bf(f - bf2f(hi));
    }
    *(short8*)(fcAh + (w*64+l)*8) = vh;
    *(short8*)(fcAl + (w*64+l)*8) = vl;
  }
  float myfcb[4];
#pragma unroll
  for (int r=0;r<4;r++){
    const int oi = quad*4 + r;
    myfcb[r] = (oi<6) ? fc_b[oi] : 0.f;
  }
  __syncthreads();

  // hoisted per-thread bias registers: myb0/myb1[gate][r]
  float myb0[4][4], myb1[4][4];
  auto load_myb = [&]{
#pragma unroll
    for (int g=0;g<4;g++)
#pragma unroll
      for (int r=0;r<4;r++){
        const int j = g*128 + w*16 + quad*4 + r;
        myb0[g][r] = bias[j];
        myb1[g][r] = bias[512 + j];
      }
  };
  load_myb();

  auto write_x = [&](int t, int p){
    if (tid < 96){
      const int n = tid & 31, c = tid >> 5;
      const float v = x[(size_t)(b0+n)*90 + t*3 + c];
      const unsigned short hi = f2bf(v);
      xbh[p*256 + n*8 + c] = hi;
      xbl[p*256 + n*8 + c] = f2bf(v - bf2f(hi));
    }
  };
  write_x(0, 0);
  __syncthreads();

  floatx4 acc[4][2];                 // [gate][nt]; 32 regs
  float c0[2][4], c1[2][4];          // [nt][r]
#pragma unroll
  for (int nt=0;nt<2;nt++)
#pragma unroll
    for (int r=0;r<4;r++){ c0[nt][r]=0.f; c1[nt][r]=0.f; }

  auto zacc = [&]{
    const floatx4 z = {0.f,0.f,0.f,0.f};
#pragma unroll
    for (int g=0;g<4;g++){ acc[g][0]=z; acc[g][1]=z; }
  };

  // acc += A(kt range, bf16) * B(h, bf16): single combo per kt.
  // Per-wave-contiguous A: one base per kt, 4 loads at +512 elem strides.
  auto mv = [&](const unsigned short* __restrict__ Ahi, int KT,
                int k0, int k1, int kboff,
                const unsigned short* Bh){
#pragma unroll 1
    for (int kt=k0; kt<k1; ++kt){
      const int bo = ((((kt-kboff)*4+quad)^n15)<<3);
      short8 bh[2];
#pragma unroll
      for (int nt=0;nt<2;nt++){
        const int ro = (nt*16+n15)*128 + bo;
        bh[nt] = *(const short8*)(Bh + ro);
      }
      const unsigned short* Aw = Ahi + ((w*KT + kt)*4)*512 + l*8;
      short8 ah[4];
#pragma unroll
      for (int g=0;g<4;g++)
        ah[g] = *(const short8*)(Aw + g*512);
      __builtin_amdgcn_s_setprio(1);
#pragma unroll
      for (int g=0;g<4;g++){
        acc[g][0] = __builtin_amdgcn_mfma_f32_16x16x32_bf16(ah[g], bh[0], acc[g][0],0,0,0);
        acc[g][1] = __builtin_amdgcn_mfma_f32_16x16x32_bf16(ah[g], bh[1], acc[g][1],0,0,0);
      }
      __builtin_amdgcn_s_setprio(0);
    }
  };

  // kt=4 of layer 0: B comes from xbuf (hi/lo kept; real data k<131, quad 0 only)
  auto mv_x = [&](const unsigned short* __restrict__ Ahi,
                  const unsigned short* Xh, const unsigned short* Xl){
    const short8 z8 = {0,0,0,0,0,0,0,0};
    short8 bh[2]={z8,z8}, bl[2]={z8,z8};
    if (quad==0){
#pragma unroll
      for (int nt=0;nt<2;nt++){
        const int ro = (nt*16+n15)*8;
        bh[nt] = *(const short8*)(Xh + ro);
        bl[nt] = *(const short8*)(Xl + ro);
      }
    }
    const unsigned short* Aw = Ahi + ((w*5 + 4)*4)*512 + l*8;
    short8 ah[4];
#pragma unroll
    for (int g=0;g<4;g++)
      ah[g] = *(const short8*)(Aw + g*512);
    __builtin_amdgcn_s_setprio(1);
#pragma unroll
    for (int g=0;g<4;g++){
      acc[g][0] = __builtin_amdgcn_mfma_f32_16x16x32_bf16(ah[g], bh[0], acc[g][0],0,0,0);
      acc[g][1] = __builtin_amdgcn_mfma_f32_16x16x32_bf16(ah[g], bh[1], acc[g][1],0,0,0);
    }
#pragma unroll
    for (int g=0;g<4;g++){
      acc[g][0] = __builtin_amdgcn_mfma_f32_16x16x32_bf16(ah[g], bl[0], acc[g][0],0,0,0);
      acc[g][1] = __builtin_amdgcn_mfma_f32_16x16x32_bf16(ah[g], bl[1], acc[g][1],0,0,0);
    }
    __builtin_amdgcn_s_setprio(0);
  };

  // activations + packed (cvt_pk) b64 h-writes to the WRITE-parity buffer.
  auto cell = [&](float (&cst)[2][4], float (&mb)[4][4], unsigned short* Hh){
    float hv[2][4];
#pragma unroll
    for (int nt=0;nt<2;nt++)
#pragma unroll
      for (int r=0;r<4;r++){
        const float i_ = sigm(acc[0][nt][r]      + mb[0][r]);
        const float f_ = sigm(acc[1][nt][r]      + mb[1][r]);
        const float g_ = tanh_fast(acc[2][nt][r] + mb[2][r]);
        const float o_ = sigm(acc[3][nt][r]      + mb[3][r]);
        const float c  = f_*cst[nt][r] + i_*g_;
        cst[nt][r] = c;
        hv[nt][r]  = o_*tanh_fast(c);
      }
#pragma unroll
    for (int nt=0;nt<2;nt++){
      const int jb = w*2 + (quad>>1);              // j>>3
      const int n  = nt*16 + n15;
      const int base = n*128 + ((jb ^ n15)<<3) + ((quad&1)<<2);
      uint2v pk;
      pk[0] = cvt_pk_bf16(hv[nt][0], hv[nt][1]);
      pk[1] = cvt_pk_bf16(hv[nt][2], hv[nt][3]);
      *(uint2v*)(Hh + base) = pk;                  // ds_write_b64
    }
  };

  // FC head via MFMA: waves 0-1 handle rows n = w*16 .. w*16+15
  auto fc = [&](int t, const unsigned short* Hh1, int xp){
    if (w < 2){
      floatx4 fa = {0.f,0.f,0.f,0.f};
#pragma unroll
      for (int kt=0;kt<4;kt++){
        const short8 ah = *(const short8*)(fcAh + (kt*64+l)*8);
        const short8 al = *(const short8*)(fcAl + (kt*64+l)*8);
        const int bo = (((kt*4+quad)^n15)<<3);
        const int ro = (w*16+n15)*128 + bo;
        const short8 bh = *(const short8*)(Hh1 + ro);
        fa = __builtin_amdgcn_mfma_f32_16x16x32_bf16(ah, bh, fa,0,0,0);
        fa = __builtin_amdgcn_mfma_f32_16x16x32_bf16(al, bh, fa,0,0,0);
      }
      const int n = w*16 + n15;
      const size_t off = (size_t)(b0+n)*90 + (size_t)t*3;
      if (quad == 0){
#pragma unroll
        for (int r=0;r<4;r++){
          const float s = fa[r] + myfcb[r];
          if (r < 3){
            out[off + r] = s;                       // mu
            const unsigned short hi = f2bf(s);      // feed mu back as next x
            xbh[xp*256 + n*8 + r] = hi;
            xbl[xp*256 + n*8 + r] = f2bf(s - bf2f(hi));
          } else {
            out[MU_OFF + off] = s;                  // logvar[0]
          }
        }
      } else if (quad == 1){
#pragma unroll
        for (int r=0;r<2;r++)
          out[MU_OFF + off + 1 + r] = fa[r] + myfcb[r];  // logvar[1,2]
      }
    }
  };

  // -------------------- encoder: 2 barriers/step --------------------
  // step t: read parity ra = t&1, write parity wa = ra^1 (h and xbuf alike)
#pragma unroll 1
  for (int t=0; t<TSTEPS; ++t){
    const int ra = (t&1)*HSZ,  wa = HSZ - ra;
    const int xr = (t&1)*256;
    // phase A: reads h0[ra], xb[ra]; writes h0[wa], xb[wa]
    zacc();
    mv  (wf+ENC0_HI, 5, 0, 4, 0, h0h+ra);
    mv_x(wf+ENC0_HI, xbh+xr, xbl+xr);
    cell(c0, myb0, h0h+wa);
    if (t+1 < TSTEPS) write_x(t+1, (t+1)&1);
    __syncthreads();                   // h0(t), x(t+1) visible
    // phase E: reads h0[wa], h1[ra]; writes h1[wa]
    zacc();
    mv(wf+ENC1_HI, 8, 0, 4, 0, h0h+wa);
    mv(wf+ENC1_HI, 8, 4, 8, 4, h1h+ra);
    cell(c1, myb1, h1h+wa);
    __syncthreads();                   // h1(t) visible
  }
  // xb[1] still holds x[:,29,:] == decoder's initial input (written at t=28)

  // ---- phase switch: dec biases into LDS, then into registers ----
  bias[tid]       = dec_b0[tid];
  bias[512 + tid] = dec_b1[tid];
  __syncthreads();
  load_myb();

  // -------------------- decoder: 3 barriers/step --------------------
  // h parity continues the enc chain (enc t=29 wrote parity 0; dec t reads t&1).
  // xbuf: dec step t reads xb[(t+1)&1], fc(t) writes xb[t&1].
#pragma unroll 1
  for (int t=0; t<TSTEPS; ++t){
    const int ra = (t&1)*HSZ,  wa = HSZ - ra;
    const int xw = (t&1)*256,  xr = 256 - xw;   // read (t+1)&1, write t&1
    // phase A
    zacc();
    mv  (wf+DEC0_HI, 5, 0, 4, 0, h0h+ra);
    mv_x(wf+DEC0_HI, xbh+xr, xbl+xr);
    cell(c0, myb0, h0h+wa);
    __syncthreads();                   // h0(t) visible
    // phase E
    zacc();
    mv(wf+DEC1_HI, 8, 0, 4, 0, h0h+wa);
    mv(wf+DEC1_HI, 8, 4, 8, 4, h1h+ra);
    cell(c1, myb1, h1h+wa);
    __syncthreads();                   // h1(t) visible
    // FC phase
    fc(t, h1h+wa, t&1);
    __syncthreads();                   // xb(t+1 input) visible
  }
}

extern "C" void kernel_launch(void* const* d_in, const int* in_sizes, int n_in,
                              void* d_out, int out_size, void* d_ws, size_t ws_size,
                              hipStream_t stream) {
  const float* x        = (const float*)d_in[0];
  const float* enc_Wih0 = (const float*)d_in[1];
  const float* enc_Whh0 = (const float*)d_in[2];
  const float* enc_b0   = (const float*)d_in[3];
  const float* enc_Wih1 = (const float*)d_in[4];
  const float* enc_Whh1 = (const float*)d_in[5];
  const float* enc_b1   = (const float*)d_in[6];
  const float* dec_Wih0 = (const float*)d_in[7];
  const float* dec_Whh0 = (const float*)d_in[8];
  const float* dec_b0   = (const float*)d_in[9];
  const float* dec_Wih1 = (const float*)d_in[10];
  const float* dec_Whh1 = (const float*)d_in[11];
  const float* dec_b1   = (const float*)d_in[12];
  const float* fc_W     = (const float*)d_in[13];
  const float* fc_b     = (const float*)d_in[14];
  unsigned short* ws = (unsigned short*)d_ws;
  float* out = (float*)d_out;

  // 425,984 (hi,lo) pairs -> exactly 1664 blocks of 256
  prep_frag<<<1664, 256, 0, stream>>>(
      enc_Wih0, enc_Whh0, enc_Wih1, enc_Whh1,
      dec_Wih0, dec_Whh0, dec_Wih1, dec_Whh1, ws);

  lstm_mfma<<<NBLK, TPB, 0, stream>>>(
      x, ws, enc_b0, enc_b1, dec_b0, dec_b1, fc_W, fc_b, out);
}

// Round 13
// 2412.912 us; speedup vs baseline: 1.2533x; 1.2533x over previous
//
#include <hip/hip_runtime.h>
#include <cstdint>

typedef short short8  __attribute__((ext_vector_type(8)));
typedef unsigned short ushort4v __attribute__((ext_vector_type(4)));
typedef unsigned int uint2v __attribute__((ext_vector_type(2)));
typedef float floatx4 __attribute__((ext_vector_type(4)));

#define HID    128
#define NB     32
#define TPB    512
#define NBLK   2048          // 65536 / 32
#define TSTEPS 30
#define MU_OFF 5898240       // 65536*30*3
#define HSZ    4096          // NB*128: one h parity buffer (bf16 units)

// ws layout (bf16 units): A-fragment arrays, PER-WAVE-CONTIGUOUS order:
// element (mt=g*8+w, kt, lane l, jj) stored at (((w*KT+kt)*4+g)*512) + l*8 + jj
// -> per kt one base add, 4 gate loads at +0/+1024/+2048/+3072 bytes (imm-foldable)
#define L0_SZ  81920         // 512*160  (K-ext: [Whh(128)|Wih0(3)|0(29)])
#define L1_SZ  131072        // 512*256  (K-ext: [Wih1(128)|Whh1(128)])
#define ENC0_HI 0
#define ENC0_LO 81920
#define ENC1_HI 163840
#define ENC1_LO 294912
#define DEC0_HI 425984
#define DEC0_LO 507904
#define DEC1_HI 589824
#define DEC1_LO 720896

// v_rcp_f32 (~1 ulp) instead of the IEEE div chain
__device__ __forceinline__ float sigm(float v){
  return __builtin_amdgcn_rcpf(1.f + __expf(-v));
}
__device__ __forceinline__ float tanh_fast(float v){
  return 2.f*__builtin_amdgcn_rcpf(1.f + __expf(-2.f*v)) - 1.f;
}

__device__ __forceinline__ unsigned short f2bf(float f){
  unsigned u = __float_as_uint(f);
  u = (u + 0x7FFF + ((u>>16)&1)) >> 16;     // RNE; inputs finite
  return (unsigned short)u;
}
__device__ __forceinline__ float bf2f(unsigned short b){
  return __uint_as_float(((unsigned)b)<<16);
}
// packed RNE f32->bf16 pair (bit-identical to f2bf for finite inputs)
__device__ __forceinline__ unsigned cvt_pk_bf16(float lo, float hi){
  unsigned r;
  asm("v_cvt_pk_bf16_f32 %0, %1, %2" : "=v"(r) : "v"(lo), "v"(hi));
  return r;
}

// ---------------- prep: swizzle weights into A-fragment order, bf16 hi/lo ----
extern "C" __global__ void __launch_bounds__(256)
prep_frag(const float* __restrict__ eWih0, const float* __restrict__ eWhh0,
          const float* __restrict__ eWih1, const float* __restrict__ eWhh1,
          const float* __restrict__ dWih0, const float* __restrict__ dWhh0,
          const float* __restrict__ dWih1, const float* __restrict__ dWhh1,
          unsigned short* __restrict__ ws)
{
  const int idx = blockIdx.x*256 + threadIdx.x;   // one thread -> one (hi,lo) pair
  int i2, hi_base, lo_base, KT;
  const float* Wa; const float* Wb;
  if (idx < L0_SZ)                { i2=idx;                 hi_base=ENC0_HI; lo_base=ENC0_LO; Wa=eWhh0; Wb=eWih0; KT=5; }
  else if (idx < L0_SZ+L1_SZ)     { i2=idx-L0_SZ;           hi_base=ENC1_HI; lo_base=ENC1_LO; Wa=eWih1; Wb=eWhh1; KT=8; }
  else if (idx < 2*L0_SZ+L1_SZ)   { i2=idx-(L0_SZ+L1_SZ);   hi_base=DEC0_HI; lo_base=DEC0_LO; Wa=dWhh0; Wb=dWih0; KT=5; }
  else                            { i2=idx-(2*L0_SZ+L1_SZ); hi_base=DEC1_HI; lo_base=DEC1_LO; Wa=dWih1; Wb=dWhh1; KT=8; }
  const int jj = i2 & 7, l = (i2>>3)&63, tk = i2>>9;
  const int kt = (KT==5) ? (tk%5) : (tk&7);
  const int mt = (KT==5) ? (tk/5) : (tk>>3);
  const int row = mt*16 + (l&15);
  const int k   = kt*32 + ((l>>4)&3)*8 + jj;
  float w;
  if (KT==5) w = (k<128) ? Wa[row*128+k] : ((k<131) ? Wb[row*3 + (k-128)] : 0.f);
  else       w = (k<128) ? Wa[row*128+k] : Wb[row*128 + (k-128)];
  const unsigned short hi = f2bf(w);
  // per-wave-contiguous output index
  const int w8 = mt & 7, g = mt >> 3;
  const int oidx = (((w8*KT + kt)*4 + g)*512) + l*8 + jj;
  ws[hi_base + oidx] = hi;
  ws[lo_base + oidx] = f2bf(w - bf2f(hi));
}

// ------- fused LSTM: NB=32/block, 8 waves, 2 blocks/CU, h in plain bf16 -----
// 2 co-resident blocks drift out of phase -> cross-block MFMA||VALU overlap
// (m114), confirmed (busy-sum 93-115% in R10/R11).
// R13 = R11 + (cvt_pk h-pack, per-wave-contiguous A layout, setprio) and
// WITHOUT R12's bias-register hoist (it spilled: 36 extra regs > 128 cap).
// Bias stays in LDS; per-gate reads merge to ds_read_b128 (affine in r).
extern "C" __global__ void __launch_bounds__(TPB, 4)
lstm_mfma(const float* __restrict__ x,
          const unsigned short* __restrict__ wf,
          const float* __restrict__ enc_b0, const float* __restrict__ enc_b1,
          const float* __restrict__ dec_b0, const float* __restrict__ dec_b1,
          const float* __restrict__ fc_W,  const float* __restrict__ fc_b,
          float* __restrict__ out)
{
  // h element (n,k) at n*128 + (((k>>3) ^ (n&15))<<3) + (k&7), per parity buf
  __shared__ unsigned short h0h[2*HSZ];
  __shared__ unsigned short h1h[2*HSZ];
  __shared__ unsigned short xbh[2*NB*8], xbl[2*NB*8]; // x / mu feedback, 2 parities
  __shared__ unsigned short fcAh[4*512], fcAl[4*512]; // FC weights, A-frag layout
  __shared__ float bias[1024];                         // current phase: [b0 | b1]

  const int tid  = threadIdx.x;
  const int w    = tid>>6, l = tid&63;
  const int quad = (l>>4)&3, n15 = l&15;
  const int b0   = blockIdx.x*NB;

  bias[tid]       = enc_b0[tid];
  bias[512 + tid] = enc_b1[tid];
  for (int i=tid;i<2*HSZ;i+=TPB){ h0h[i]=0; h1h[i]=0; }
  xbh[tid]=0; xbl[tid]=0;                   // 2*NB*8 == 512 == TPB
  if (w < 4){                               // FC weights -> LDS A-frags, kt=w
    short8 vh, vl;
#pragma unroll
    for (int jj=0;jj<8;jj++){
      const float f = (n15<6) ? fc_W[n15*HID + w*32 + quad*8 + jj] : 0.f;
      const unsigned short hi = f2bf(f);
      vh[jj] = (short)hi;
      vl[jj] = (short)f2bf(f - bf2f(hi));
    }
    *(short8*)(fcAh + (w*64+l)*8) = vh;
    *(short8*)(fcAl + (w*64+l)*8) = vl;
  }
  float myfcb[4];
#pragma unroll
  for (int r=0;r<4;r++){
    const int oi = quad*4 + r;
    myfcb[r] = (oi<6) ? fc_b[oi] : 0.f;
  }
  __syncthreads();

  auto write_x = [&](int t, int p){
    if (tid < 96){
      const int n = tid & 31, c = tid >> 5;
      const float v = x[(size_t)(b0+n)*90 + t*3 + c];
      const unsigned short hi = f2bf(v);
      xbh[p*256 + n*8 + c] = hi;
      xbl[p*256 + n*8 + c] = f2bf(v - bf2f(hi));
    }
  };
  write_x(0, 0);
  __syncthreads();

  floatx4 acc[4][2];                 // [gate][nt]; 32 regs
  float c0[2][4], c1[2][4];          // [nt][r]
#pragma unroll
  for (int nt=0;nt<2;nt++)
#pragma unroll
    for (int r=0;r<4;r++){ c0[nt][r]=0.f; c1[nt][r]=0.f; }

  auto zacc = [&]{
    const floatx4 z = {0.f,0.f,0.f,0.f};
#pragma unroll
    for (int g=0;g<4;g++){ acc[g][0]=z; acc[g][1]=z; }
  };

  // acc += A(kt range, bf16) * B(h, bf16): single combo per kt.
  // Per-wave-contiguous A: one base per kt, 4 loads at +512 elem strides.
  auto mv = [&](const unsigned short* __restrict__ Ahi, int KT,
                int k0, int k1, int kboff,
                const unsigned short* Bh){
#pragma unroll 1
    for (int kt=k0; kt<k1; ++kt){
      const int bo = ((((kt-kboff)*4+quad)^n15)<<3);
      short8 bh[2];
#pragma unroll
      for (int nt=0;nt<2;nt++){
        const int ro = (nt*16+n15)*128 + bo;
        bh[nt] = *(const short8*)(Bh + ro);
      }
      const unsigned short* Aw = Ahi + ((w*KT + kt)*4)*512 + l*8;
      short8 ah[4];
#pragma unroll
      for (int g=0;g<4;g++)
        ah[g] = *(const short8*)(Aw + g*512);
      __builtin_amdgcn_s_setprio(1);
#pragma unroll
      for (int g=0;g<4;g++){
        acc[g][0] = __builtin_amdgcn_mfma_f32_16x16x32_bf16(ah[g], bh[0], acc[g][0],0,0,0);
        acc[g][1] = __builtin_amdgcn_mfma_f32_16x16x32_bf16(ah[g], bh[1], acc[g][1],0,0,0);
      }
      __builtin_amdgcn_s_setprio(0);
    }
  };

  // kt=4 of layer 0: B comes from xbuf (hi/lo kept; real data k<131, quad 0 only)
  auto mv_x = [&](const unsigned short* __restrict__ Ahi,
                  const unsigned short* Xh, const unsigned short* Xl){
    const short8 z8 = {0,0,0,0,0,0,0,0};
    short8 bh[2]={z8,z8}, bl[2]={z8,z8};
    if (quad==0){
#pragma unroll
      for (int nt=0;nt<2;nt++){
        const int ro = (nt*16+n15)*8;
        bh[nt] = *(const short8*)(Xh + ro);
        bl[nt] = *(const short8*)(Xl + ro);
      }
    }
    const unsigned short* Aw = Ahi + ((w*5 + 4)*4)*512 + l*8;
    short8 ah[4];
#pragma unroll
    for (int g=0;g<4;g++)
      ah[g] = *(const short8*)(Aw + g*512);
    __builtin_amdgcn_s_setprio(1);
#pragma unroll
    for (int g=0;g<4;g++){
      acc[g][0] = __builtin_amdgcn_mfma_f32_16x16x32_bf16(ah[g], bh[0], acc[g][0],0,0,0);
      acc[g][1] = __builtin_amdgcn_mfma_f32_16x16x32_bf16(ah[g], bh[1], acc[g][1],0,0,0);
    }
#pragma unroll
    for (int g=0;g<4;g++){
      acc[g][0] = __builtin_amdgcn_mfma_f32_16x16x32_bf16(ah[g], bl[0], acc[g][0],0,0,0);
      acc[g][1] = __builtin_amdgcn_mfma_f32_16x16x32_bf16(ah[g], bl[1], acc[g][1],0,0,0);
    }
    __builtin_amdgcn_s_setprio(0);
  };

  // activations + packed (cvt_pk) b64 h-writes to the WRITE-parity buffer.
  // No internal barrier: in-interval readers touch the other parity only.
  auto cell = [&](float (&cst)[2][4], int boff, unsigned short* Hh){
    float hv[2][4];
#pragma unroll
    for (int nt=0;nt<2;nt++)
#pragma unroll
      for (int r=0;r<4;r++){
        const int j = w*16 + quad*4 + r;
        const float i_ = sigm(acc[0][nt][r]      + bias[boff       + j]);
        const float f_ = sigm(acc[1][nt][r]      + bias[boff + 128 + j]);
        const float g_ = tanh_fast(acc[2][nt][r] + bias[boff + 256 + j]);
        const float o_ = sigm(acc[3][nt][r]      + bias[boff + 384 + j]);
        const float c  = f_*cst[nt][r] + i_*g_;
        cst[nt][r] = c;
        hv[nt][r]  = o_*tanh_fast(c);
      }
#pragma unroll
    for (int nt=0;nt<2;nt++){
      const int jb = w*2 + (quad>>1);              // j>>3
      const int n  = nt*16 + n15;
      const int base = n*128 + ((jb ^ n15)<<3) + ((quad&1)<<2);
      uint2v pk;
      pk[0] = cvt_pk_bf16(hv[nt][0], hv[nt][1]);
      pk[1] = cvt_pk_bf16(hv[nt][2], hv[nt][3]);
      *(uint2v*)(Hh + base) = pk;                  // ds_write_b64
    }
  };

  // FC head via MFMA: waves 0-1 handle rows n = w*16 .. w*16+15
  auto fc = [&](int t, const unsigned short* Hh1, int xp){
    if (w < 2){
      floatx4 fa = {0.f,0.f,0.f,0.f};
#pragma unroll
      for (int kt=0;kt<4;kt++){
        const short8 ah = *(const short8*)(fcAh + (kt*64+l)*8);
        const short8 al = *(const short8*)(fcAl + (kt*64+l)*8);
        const int bo = (((kt*4+quad)^n15)<<3);
        const int ro = (w*16+n15)*128 + bo;
        const short8 bh = *(const short8*)(Hh1 + ro);
        fa = __builtin_amdgcn_mfma_f32_16x16x32_bf16(ah, bh, fa,0,0,0);
        fa = __builtin_amdgcn_mfma_f32_16x16x32_bf16(al, bh, fa,0,0,0);
      }
      const int n = w*16 + n15;
      const size_t off = (size_t)(b0+n)*90 + (size_t)t*3;
      if (quad == 0){
#pragma unroll
        for (int r=0;r<4;r++){
          const float s = fa[r] + myfcb[r];
          if (r < 3){
            out[off + r] = s;                       // mu
            const unsigned short hi = f2bf(s);      // feed mu back as next x
            xbh[xp*256 + n*8 + r] = hi;
            xbl[xp*256 + n*8 + r] = f2bf(s - bf2f(hi));
          } else {
            out[MU_OFF + off] = s;                  // logvar[0]
          }
        }
      } else if (quad == 1){
#pragma unroll
        for (int r=0;r<2;r++)
          out[MU_OFF + off + 1 + r] = fa[r] + myfcb[r];  // logvar[1,2]
      }
    }
  };

  // -------------------- encoder: 2 barriers/step --------------------
  // step t: read parity ra = t&1, write parity wa = ra^1 (h and xbuf alike)
#pragma unroll 1
  for (int t=0; t<TSTEPS; ++t){
    const int ra = (t&1)*HSZ,  wa = HSZ - ra;
    const int xr = (t&1)*256;
    // phase A: reads h0[ra], xb[ra]; writes h0[wa], xb[wa]
    zacc();
    mv  (wf+ENC0_HI, 5, 0, 4, 0, h0h+ra);
    mv_x(wf+ENC0_HI, xbh+xr, xbl+xr);
    cell(c0, 0, h0h+wa);
    if (t+1 < TSTEPS) write_x(t+1, (t+1)&1);
    __syncthreads();                   // h0(t), x(t+1) visible
    // phase E: reads h0[wa], h1[ra]; writes h1[wa]
    zacc();
    mv(wf+ENC1_HI, 8, 0, 4, 0, h0h+wa);
    mv(wf+ENC1_HI, 8, 4, 8, 4, h1h+ra);
    cell(c1, 512, h1h+wa);
    __syncthreads();                   // h1(t) visible
  }
  // xb[1] still holds x[:,29,:] == decoder's initial input (written at t=28)

  // ---- phase switch: dec biases into LDS ----
  bias[tid]       = dec_b0[tid];
  bias[512 + tid] = dec_b1[tid];
  __syncthreads();

  // -------------------- decoder: 3 barriers/step --------------------
  // h parity continues the enc chain (enc t=29 wrote parity 0; dec t reads t&1).
  // xbuf: dec step t reads xb[(t+1)&1], fc(t) writes xb[t&1].
#pragma unroll 1
  for (int t=0; t<TSTEPS; ++t){
    const int ra = (t&1)*HSZ,  wa = HSZ - ra;
    const int xw = (t&1)*256,  xr = 256 - xw;   // read (t+1)&1, write t&1
    // phase A
    zacc();
    mv  (wf+DEC0_HI, 5, 0, 4, 0, h0h+ra);
    mv_x(wf+DEC0_HI, xbh+xr, xbl+xr);
    cell(c0, 0, h0h+wa);
    __syncthreads();                   // h0(t) visible
    // phase E
    zacc();
    mv(wf+DEC1_HI, 8, 0, 4, 0, h0h+wa);
    mv(wf+DEC1_HI, 8, 4, 8, 4, h1h+ra);
    cell(c1, 512, h1h+wa);
    __syncthreads();                   // h1(t) visible
    // FC phase
    fc(t, h1h+wa, t&1);
    __syncthreads();                   // xb(t+1 input) visible
  }
}

extern "C" void kernel_launch(void* const* d_in, const int* in_sizes, int n_in,
                              void* d_out, int out_size, void* d_ws, size_t ws_size,
                              hipStream_t stream) {
  const float* x        = (const float*)d_in[0];
  const float* enc_Wih0 = (const float*)d_in[1];
  const float* enc_Whh0 = (const float*)d_in[2];
  const float* enc_b0   = (const float*)d_in[3];
  const float* enc_Wih1 = (const float*)d_in[4];
  const float* enc_Whh1 = (const float*)d_in[5];
  const float* enc_b1   = (const float*)d_in[6];
  const float* dec_Wih0 = (const float*)d_in[7];
  const float* dec_Whh0 = (const float*)d_in[8];
  const float* dec_b0   = (const float*)d_in[9];
  const float* dec_Wih1 = (const float*)d_in[10];
  const float* dec_Whh1 = (const float*)d_in[11];
  const float* dec_b1   = (const float*)d_in[12];
  const float* fc_W     = (const float*)d_in[13];
  const float* fc_b     = (const float*)d_in[14];
  unsigned short* ws = (unsigned short*)d_ws;
  float* out = (float*)d_out;

  // 425,984 (hi,lo) pairs -> exactly 1664 blocks of 256
  prep_frag<<<1664, 256, 0, stream>>>(
      enc_Wih0, enc_Whh0, enc_Wih1, enc_Whh1,
      dec_Wih0, dec_Whh0, dec_Wih1, dec_Whh1, ws);

  lstm_mfma<<<NBLK, TPB, 0, stream>>>(
      x, ws, enc_b0, enc_b1, dec_b0, dec_b1, fc_W, fc_b, out);
}

// Round 15
// 2190.278 us; speedup vs baseline: 1.3807x; 1.1016x over previous
//
#include <hip/hip_runtime.h>
#include <cstdint>

typedef short short8  __attribute__((ext_vector_type(8)));
typedef unsigned short ushort4v __attribute__((ext_vector_type(4)));
typedef unsigned int uint2v __attribute__((ext_vector_type(2)));
typedef float floatx4 __attribute__((ext_vector_type(4)));

#define HID    128
#define NB     32
#define TPB    512
#define NBLK   2048          // 65536 / 32
#define TSTEPS 30
#define MU_OFF 5898240       // 65536*30*3
#define HSZ    4096          // NB*128: one h parity buffer (bf16 units)

#define LOG2E  1.4426950408889634f
#define LOG2E2 2.8853900817779268f

// ws layout (bf16 units): A-fragment arrays, PER-WAVE-CONTIGUOUS order:
// element (mt=g*8+w, kt, lane l, jj) stored at (((w*KT+kt)*4+g)*512) + l*8 + jj
// Gate weights PRE-SCALED: i,f,o rows by log2e; g rows by 2*log2e -> act uses
// bare v_exp_f32 (exp2) with no per-element multiply.
#define L0_SZ  81920         // 512*160  (K-ext: [Whh(128)|Wih0(3)|0(29)])
#define L1_SZ  131072        // 512*256  (K-ext: [Wih1(128)|Whh1(128)])
#define ENC0_HI 0
#define ENC0_LO 81920
#define ENC1_HI 163840
#define ENC1_LO 294912
#define DEC0_HI 425984
#define DEC0_LO 507904
#define DEC1_HI 589824
#define DEC1_LO 720896

__device__ __forceinline__ unsigned short f2bf(float f){
  unsigned u = __float_as_uint(f);
  u = (u + 0x7FFF + ((u>>16)&1)) >> 16;     // RNE; inputs finite
  return (unsigned short)u;
}
__device__ __forceinline__ float bf2f(unsigned short b){
  return __uint_as_float(((unsigned)b)<<16);
}
// packed RNE f32->bf16 pair (bit-identical to f2bf for finite inputs)
__device__ __forceinline__ unsigned cvt_pk_bf16(float lo, float hi){
  unsigned r;
  asm("v_cvt_pk_bf16_f32 %0, %1, %2" : "=v"(r) : "v"(lo), "v"(hi));
  return r;
}

// ---------------- prep: swizzle weights into A-fragment order, bf16 hi/lo ----
extern "C" __global__ void __launch_bounds__(256)
prep_frag(const float* __restrict__ eWih0, const float* __restrict__ eWhh0,
          const float* __restrict__ eWih1, const float* __restrict__ eWhh1,
          const float* __restrict__ dWih0, const float* __restrict__ dWhh0,
          const float* __restrict__ dWih1, const float* __restrict__ dWhh1,
          unsigned short* __restrict__ ws)
{
  const int idx = blockIdx.x*256 + threadIdx.x;   // one thread -> one (hi,lo) pair
  int i2, hi_base, lo_base, KT;
  const float* Wa; const float* Wb;
  if (idx < L0_SZ)                { i2=idx;                 hi_base=ENC0_HI; lo_base=ENC0_LO; Wa=eWhh0; Wb=eWih0; KT=5; }
  else if (idx < L0_SZ+L1_SZ)     { i2=idx-L0_SZ;           hi_base=ENC1_HI; lo_base=ENC1_LO; Wa=eWih1; Wb=eWhh1; KT=8; }
  else if (idx < 2*L0_SZ+L1_SZ)   { i2=idx-(L0_SZ+L1_SZ);   hi_base=DEC0_HI; lo_base=DEC0_LO; Wa=dWhh0; Wb=dWih0; KT=5; }
  else                            { i2=idx-(2*L0_SZ+L1_SZ); hi_base=DEC1_HI; lo_base=DEC1_LO; Wa=dWih1; Wb=dWhh1; KT=8; }
  const int jj = i2 & 7, l = (i2>>3)&63, tk = i2>>9;
  const int kt = (KT==5) ? (tk%5) : (tk&7);
  const int mt = (KT==5) ? (tk/5) : (tk>>3);
  const int row = mt*16 + (l&15);
  const int k   = kt*32 + ((l>>4)&3)*8 + jj;
  float w;
  if (KT==5) w = (k<128) ? Wa[row*128+k] : ((k<131) ? Wb[row*3 + (k-128)] : 0.f);
  else       w = (k<128) ? Wa[row*128+k] : Wb[row*128 + (k-128)];
  // gate pre-scale: i,f,o -> log2e; g -> 2*log2e
  const int g = mt >> 3;
  w *= (g==2) ? LOG2E2 : LOG2E;
  const unsigned short hi = f2bf(w);
  // per-wave-contiguous output index
  const int w8 = mt & 7;
  const int oidx = (((w8*KT + kt)*4 + g)*512) + l*8 + jj;
  ws[hi_base + oidx] = hi;
  ws[lo_base + oidx] = f2bf(w - bf2f(hi));
}

// ------- fused LSTM: NB=32/block, 8 waves, 2 blocks/CU, h in plain bf16 -----
// 2 co-resident blocks drift out of phase -> cross-block MFMA||VALU overlap
// (m114), confirmed (busy-sum 104% R13).
// R14 vs R13: activation algebra rewritten in product form with pre-scaled
// weights: 8 trans/elem (was 10), no exp-input multiplies.
//   sigma(a)*tanh(b) = (1-e_b) / [(1+e_a)(1+e_b)],  e_x = exp2(-ax')
extern "C" __global__ void __launch_bounds__(TPB, 4)
lstm_mfma(const float* __restrict__ x,
          const unsigned short* __restrict__ wf,
          const float* __restrict__ enc_b0, const float* __restrict__ enc_b1,
          const float* __restrict__ dec_b0, const float* __restrict__ dec_b1,
          const float* __restrict__ fc_W,  const float* __restrict__ fc_b,
          float* __restrict__ out)
{
  // h element (n,k) at n*128 + (((k>>3) ^ (n&15))<<3) + (k&7), per parity buf
  __shared__ unsigned short h0h[2*HSZ];
  __shared__ unsigned short h1h[2*HSZ];
  __shared__ unsigned short xbh[2*NB*8], xbl[2*NB*8]; // x / mu feedback, 2 parities
  __shared__ unsigned short fcAh[4*512], fcAl[4*512]; // FC weights, A-frag layout
  __shared__ float bias[1024];                         // current phase: [b0 | b1], pre-scaled

  const int tid  = threadIdx.x;
  const int w    = tid>>6, l = tid&63;
  const int quad = (l>>4)&3, n15 = l&15;
  const int b0   = blockIdx.x*NB;

  const float bsc = (((tid>>7)&3)==2) ? LOG2E2 : LOG2E;
  bias[tid]       = enc_b0[tid] * bsc;
  bias[512 + tid] = enc_b1[tid] * bsc;
  for (int i=tid;i<2*HSZ;i+=TPB){ h0h[i]=0; h1h[i]=0; }
  xbh[tid]=0; xbl[tid]=0;                   // 2*NB*8 == 512 == TPB
  if (w < 4){                               // FC weights -> LDS A-frags, kt=w
    short8 vh, vl;
#pragma unroll
    for (int jj=0;jj<8;jj++){
      const float f = (n15<6) ? fc_W[n15*HID + w*32 + quad*8 + jj] : 0.f;
      const unsigned short hi = f2bf(f);
      vh[jj] = (short)hi;
      vl[jj] = (short)f2bf(f - bf2f(hi));
    }
    *(short8*)(fcAh + (w*64+l)*8) = vh;
    *(short8*)(fcAl + (w*64+l)*8) = vl;
  }
  float myfcb[4];
#pragma unroll
  for (int r=0;r<4;r++){
    const int oi = quad*4 + r;
    myfcb[r] = (oi<6) ? fc_b[oi] : 0.f;
  }
  __syncthreads();

  auto write_x = [&](int t, int p){
    if (tid < 96){
      const int n = tid & 31, c = tid >> 5;
      const float v = x[(size_t)(b0+n)*90 + t*3 + c];
      const unsigned short hi = f2bf(v);
      xbh[p*256 + n*8 + c] = hi;
      xbl[p*256 + n*8 + c] = f2bf(v - bf2f(hi));
    }
  };
  write_x(0, 0);
  __syncthreads();

  floatx4 acc[4][2];                 // [gate][nt]; 32 regs
  float c0[2][4], c1[2][4];          // [nt][r]
#pragma unroll
  for (int nt=0;nt<2;nt++)
#pragma unroll
    for (int r=0;r<4;r++){ c0[nt][r]=0.f; c1[nt][r]=0.f; }

  auto zacc = [&]{
    const floatx4 z = {0.f,0.f,0.f,0.f};
#pragma unroll
    for (int g=0;g<4;g++){ acc[g][0]=z; acc[g][1]=z; }
  };

  // acc += A(kt range, bf16) * B(h, bf16): single combo per kt.
  // Per-wave-contiguous A: one base per kt, 4 loads at +512 elem strides.
  auto mv = [&](const unsigned short* __restrict__ Ahi, int KT,
                int k0, int k1, int kboff,
                const unsigned short* Bh){
#pragma unroll 1
    for (int kt=k0; kt<k1; ++kt){
      const int bo = ((((kt-kboff)*4+quad)^n15)<<3);
      short8 bh[2];
#pragma unroll
      for (int nt=0;nt<2;nt++){
        const int ro = (nt*16+n15)*128 + bo;
        bh[nt] = *(const short8*)(Bh + ro);
      }
      const unsigned short* Aw = Ahi + ((w*KT + kt)*4)*512 + l*8;
      short8 ah[4];
#pragma unroll
      for (int g=0;g<4;g++)
        ah[g] = *(const short8*)(Aw + g*512);
      __builtin_amdgcn_s_setprio(1);
#pragma unroll
      for (int g=0;g<4;g++){
        acc[g][0] = __builtin_amdgcn_mfma_f32_16x16x32_bf16(ah[g], bh[0], acc[g][0],0,0,0);
        acc[g][1] = __builtin_amdgcn_mfma_f32_16x16x32_bf16(ah[g], bh[1], acc[g][1],0,0,0);
      }
      __builtin_amdgcn_s_setprio(0);
    }
  };

  // kt=4 of layer 0: B comes from xbuf (hi/lo kept; real data k<131, quad 0 only)
  auto mv_x = [&](const unsigned short* __restrict__ Ahi,
                  const unsigned short* Xh, const unsigned short* Xl){
    const short8 z8 = {0,0,0,0,0,0,0,0};
    short8 bh[2]={z8,z8}, bl[2]={z8,z8};
    if (quad==0){
#pragma unroll
      for (int nt=0;nt<2;nt++){
        const int ro = (nt*16+n15)*8;
        bh[nt] = *(const short8*)(Xh + ro);
        bl[nt] = *(const short8*)(Xl + ro);
      }
    }
    const unsigned short* Aw = Ahi + ((w*5 + 4)*4)*512 + l*8;
    short8 ah[4];
#pragma unroll
    for (int g=0;g<4;g++)
      ah[g] = *(const short8*)(Aw + g*512);
    __builtin_amdgcn_s_setprio(1);
#pragma unroll
    for (int g=0;g<4;g++){
      acc[g][0] = __builtin_amdgcn_mfma_f32_16x16x32_bf16(ah[g], bh[0], acc[g][0],0,0,0);
      acc[g][1] = __builtin_amdgcn_mfma_f32_16x16x32_bf16(ah[g], bh[1], acc[g][1],0,0,0);
    }
#pragma unroll
    for (int g=0;g<4;g++){
      acc[g][0] = __builtin_amdgcn_mfma_f32_16x16x32_bf16(ah[g], bl[0], acc[g][0],0,0,0);
      acc[g][1] = __builtin_amdgcn_mfma_f32_16x16x32_bf16(ah[g], bl[1], acc[g][1],0,0,0);
    }
    __builtin_amdgcn_s_setprio(0);
  };

  // activations (product-form, 8 trans/elem) + packed cvt_pk b64 h-writes.
  // Pre-activations arrive pre-scaled: i,f,o by log2e; g by 2*log2e.
  //   i*g       = (1-eg) / [(1+ei)(1+eg)]
  //   o*tanh(c) = (1-ec) / [(1+eo)(1+ec)],  ec = exp2(-2*log2e*c)
  auto cell = [&](float (&cst)[2][4], int boff, unsigned short* Hh){
    float hv[2][4];
#pragma unroll
    for (int nt=0;nt<2;nt++)
#pragma unroll
      for (int r=0;r<4;r++){
        const int j = w*16 + quad*4 + r;
        const float ai = acc[0][nt][r] + bias[boff       + j];
        const float af = acc[1][nt][r] + bias[boff + 128 + j];
        const float ag = acc[2][nt][r] + bias[boff + 256 + j];
        const float ao = acc[3][nt][r] + bias[boff + 384 + j];
        const float ei = __builtin_amdgcn_exp2f(-ai);
        const float ef = __builtin_amdgcn_exp2f(-af);
        const float eg = __builtin_amdgcn_exp2f(-ag);
        const float eo = __builtin_amdgcn_exp2f(-ao);
        const float f_ = __builtin_amdgcn_rcpf(1.f + ef);
        const float ig = (1.f - eg) * __builtin_amdgcn_rcpf((1.f + ei)*(1.f + eg));
        const float c  = f_*cst[nt][r] + ig;
        cst[nt][r] = c;
        const float ec = __builtin_amdgcn_exp2f(c * (-LOG2E2));
        hv[nt][r] = (1.f - ec) * __builtin_amdgcn_rcpf((1.f + eo)*(1.f + ec));
      }
#pragma unroll
    for (int nt=0;nt<2;nt++){
      const int jb = w*2 + (quad>>1);              // j>>3
      const int n  = nt*16 + n15;
      const int base = n*128 + ((jb ^ n15)<<3) + ((quad&1)<<2);
      uint2v pk;
      pk[0] = cvt_pk_bf16(hv[nt][0], hv[nt][1]);
      pk[1] = cvt_pk_bf16(hv[nt][2], hv[nt][3]);
      *(uint2v*)(Hh + base) = pk;                  // ds_write_b64
    }
  };

  // FC head via MFMA: waves 0-1 handle rows n = w*16 .. w*16+15
  auto fc = [&](int t, const unsigned short* Hh1, int xp){
    if (w < 2){
      floatx4 fa = {0.f,0.f,0.f,0.f};
#pragma unroll
      for (int kt=0;kt<4;kt++){
        const short8 ah = *(const short8*)(fcAh + (kt*64+l)*8);
        const short8 al = *(const short8*)(fcAl + (kt*64+l)*8);
        const int bo = (((kt*4+quad)^n15)<<3);
        const int ro = (w*16+n15)*128 + bo;
        const short8 bh = *(const short8*)(Hh1 + ro);
        fa = __builtin_amdgcn_mfma_f32_16x16x32_bf16(ah, bh, fa,0,0,0);
        fa = __builtin_amdgcn_mfma_f32_16x16x32_bf16(al, bh, fa,0,0,0);
      }
      const int n = w*16 + n15;
      const size_t off = (size_t)(b0+n)*90 + (size_t)t*3;
      if (quad == 0){
#pragma unroll
        for (int r=0;r<4;r++){
          const float s = fa[r] + myfcb[r];
          if (r < 3){
            out[off + r] = s;                       // mu
            const unsigned short hi = f2bf(s);      // feed mu back as next x
            xbh[xp*256 + n*8 + r] = hi;
            xbl[xp*256 + n*8 + r] = f2bf(s - bf2f(hi));
          } else {
            out[MU_OFF + off] = s;                  // logvar[0]
          }
        }
      } else if (quad == 1){
#pragma unroll
        for (int r=0;r<2;r++)
          out[MU_OFF + off + 1 + r] = fa[r] + myfcb[r];  // logvar[1,2]
      }
    }
  };

  // -------------------- encoder: 2 barriers/step --------------------
  // step t: read parity ra = t&1, write parity wa = ra^1 (h and xbuf alike)
#pragma unroll 1
  for (int t=0; t<TSTEPS; ++t){
    const int ra = (t&1)*HSZ,  wa = HSZ - ra;
    const int xr = (t&1)*256;
    // phase A: reads h0[ra], xb[ra]; writes h0[wa], xb[wa]
    zacc();
    mv  (wf+ENC0_HI, 5, 0, 4, 0, h0h+ra);
    mv_x(wf+ENC0_HI, xbh+xr, xbl+xr);
    cell(c0, 0, h0h+wa);
    if (t+1 < TSTEPS) write_x(t+1, (t+1)&1);
    __syncthreads();                   // h0(t), x(t+1) visible
    // phase E: reads h0[wa], h1[ra]; writes h1[wa]
    zacc();
    mv(wf+ENC1_HI, 8, 0, 4, 0, h0h+wa);
    mv(wf+ENC1_HI, 8, 4, 8, 4, h1h+ra);
    cell(c1, 512, h1h+wa);
    __syncthreads();                   // h1(t) visible
  }
  // xb[1] still holds x[:,29,:] == decoder's initial input (written at t=28)

  // ---- phase switch: dec biases into LDS (pre-scaled) ----
  bias[tid]       = dec_b0[tid] * bsc;
  bias[512 + tid] = dec_b1[tid] * bsc;
  __syncthreads();

  // -------------------- decoder: 3 barriers/step --------------------
  // h parity continues the enc chain (enc t=29 wrote parity 0; dec t reads t&1).
  // xbuf: dec step t reads xb[(t+1)&1], fc(t) writes xb[t&1].
#pragma unroll 1
  for (int t=0; t<TSTEPS; ++t){
    const int ra = (t&1)*HSZ,  wa = HSZ - ra;
    const int xw = (t&1)*256,  xr = 256 - xw;   // read (t+1)&1, write t&1
    // phase A
    zacc();
    mv  (wf+DEC0_HI, 5, 0, 4, 0, h0h+ra);
    mv_x(wf+DEC0_HI, xbh+xr, xbl+xr);
    cell(c0, 0, h0h+wa);
    __syncthreads();                   // h0(t) visible
    // phase E
    zacc();
    mv(wf+DEC1_HI, 8, 0, 4, 0, h0h+wa);
    mv(wf+DEC1_HI, 8, 4, 8, 4, h1h+ra);
    cell(c1, 512, h1h+wa);
    __syncthreads();                   // h1(t) visible
    // FC phase
    fc(t, h1h+wa, t&1);
    __syncthreads();                   // xb(t+1 input) visible
  }
}

extern "C" void kernel_launch(void* const* d_in, const int* in_sizes, int n_in,
                              void* d_out, int out_size, void* d_ws, size_t ws_size,
                              hipStream_t stream) {
  const float* x        = (const float*)d_in[0];
  const float* enc_Wih0 = (const float*)d_in[1];
  const float* enc_Whh0 = (const float*)d_in[2];
  const float* enc_b0   = (const float*)d_in[3];
  const float* enc_Wih1 = (const float*)d_in[4];
  const float* enc_Whh1 = (const float*)d_in[5];
  const float* enc_b1   = (const float*)d_in[6];
  const float* dec_Wih0 = (const float*)d_in[7];
  const float* dec_Whh0 = (const float*)d_in[8];
  const float* dec_b0   = (const float*)d_in[9];
  const float* dec_Wih1 = (const float*)d_in[10];
  const float* dec_Whh1 = (const float*)d_in[11];
  const float* dec_b1   = (const float*)d_in[12];
  const float* fc_W     = (const float*)d_in[13];
  const float* fc_b     = (const float*)d_in[14];
  unsigned short* ws = (unsigned short*)d_ws;
  float* out = (float*)d_out;

  // 425,984 (hi,lo) pairs -> exactly 1664 blocks of 256
  prep_frag<<<1664, 256, 0, stream>>>(
      enc_Wih0, enc_Whh0, enc_Wih1, enc_Whh1,
      dec_Wih0, dec_Whh0, dec_Wih1, dec_Whh1, ws);

  lstm_mfma<<<NBLK, TPB, 0, stream>>>(
      x, ws, enc_b0, enc_b1, dec_b0, dec_b1, fc_W, fc_b, out);
}